// Round 10
// baseline (587.348 us; speedup 1.0000x reference)
//
#include <hip/hip_runtime.h>
#include <math.h>

#define MC      16384
#define NSTEPS  120
#define PER     30
#define NMAT    4
#define NSTR    21
#define RRATE   0.05f
#define NBLK    512
#define NSAMP   32

typedef short short8  __attribute__((ext_vector_type(8)));
typedef short short4v __attribute__((ext_vector_type(4)));
typedef float f32x4   __attribute__((ext_vector_type(4)));

// ws layout (floats)
#define WS_PRPART 0                         // [84][2][512]
#define WS_EPART  (NMAT*NSTR*2*NBLK)        // [2048] per-wave partial e-sums
#define WS_MEANE  (WS_EPART + 2048)         // [1]

// out layout (floats)
#define OUT_PV    0
#define OUT_PVV   84
#define OUT_PEXO  168
#define OUT_MEAN  16552
#define OUT_VAR   16553
#define OUT_ERR   16554

__device__ __forceinline__ float tgridf(int i)  { return (float)((double)i * (1.0/120.0)); }
__device__ __forceinline__ float strikef(int s) { return (float)(0.8 + (double)s * 0.02); }
__device__ __forceinline__ float softplusf(float x){
  return fmaxf(x, 0.0f) + log1pf(expf(-fabsf(x)));
}
__device__ __forceinline__ unsigned short f2bf(float f){
  unsigned u = __builtin_bit_cast(unsigned, f);
  unsigned r = (u + 0x7FFFu + ((u>>16)&1u)) >> 16;
  return (unsigned short)r;
}
__device__ __forceinline__ float bf2f(unsigned short u){
  return __builtin_bit_cast(float, ((unsigned)u)<<16);
}
// swizzled byte addr in a [16 rows x 128 cols] bf16 tile (256 B/row, 16 slots of 16B)
__device__ __forceinline__ int swaddr(int row, int slot, int inner){
  return row*256 + (((slot + row) & 15) << 4) + inner;
}
__device__ __forceinline__ short8 rdA(const unsigned short* H, int mt, int base, int lane){
  int addr = swaddr(mt*16 + (lane&15), base + (lane>>4), 0);
  return *(const short8*)((const char*)H + addr);
}
__device__ __forceinline__ f32x4 mm(short8 a, short8 b, f32x4 c){
  return __builtin_amdgcn_mfma_f32_16x16x32_bf16(a, b, c, 0, 0, 0);
}
// D-store (relu); bias folded via constant-1 K-row
__device__ __forceinline__ void stD(unsigned short* H, int colbase, int mt, int lane,
                                    f32x4 acc, bool relu){
  int col  = colbase + (lane & 15);
  int slot = col >> 3, inner = (col & 7)*2;
  #pragma unroll
  for (int i2=0;i2<4;++i2){
    int rw = mt*16 + ((lane>>4)<<2) + i2;
    float v = acc[i2];
    if (relu) v = fmaxf(v, 0.0f);
    *(unsigned short*)((char*)H + swaddr(rw, slot, inner)) = f2bf(v);
  }
}
// d-net B frag with bias row at k==50 and 1-propagator at (50,50)
__device__ __forceinline__ short8 mkBd(const float* __restrict__ W, const float* __restrict__ bias,
                                       int n0, int kt, int lane){
  short8 r;
  int n = n0 + (lane&15);
  #pragma unroll
  for (int i2=0;i2<8;++i2){
    int k = kt*32 + ((lane>>4)<<3) + i2;
    float w;
    if (k<50)       w = (n<50)? W[k*50+n] : 0.f;
    else if (k==50) w = (n<50)? bias[n] : ((n==50)? 1.f : 0.f);
    else            w = 0.f;
    r[i2] = (short)f2bf(w);
  }
  return r;
}
// v/e-net B frag (single K-tile) with bias row at k==KV, 1-propagator at (KV,KV)
__device__ __forceinline__ short8 mkBq(const float* __restrict__ W, const float* __restrict__ bias,
                                       int KV, int n0, int lane){
  short8 r;
  int n = n0 + (lane&15);
  #pragma unroll
  for (int i2=0;i2<8;++i2){
    int k = ((lane>>4)<<3) + i2;
    float w;
    if (k<KV)       w = (n<KV)? W[k*KV+n] : 0.f;
    else if (k==KV) w = (n<KV)? bias[n] : ((n==KV)? 1.f : 0.f);
    else            w = 0.f;
    r[i2] = (short)f2bf(w);
  }
  return r;
}
// one full layer for all three nets, within a single wave (no barriers)
__device__ __forceinline__ void layer_all(const unsigned short* src, unsigned short* dst,
                                          const short8 (*__restrict__ Bd)[64],
                                          const short8 (*__restrict__ Bv)[64],
                                          const short8 (*__restrict__ Be)[64],
                                          int l, int lane){
  short8 a0 = rdA(src,0,0,lane), a1 = rdA(src,0,4,lane);
  short8 av = rdA(src,0,8,lane);
  short8 ae = rdA(src,0,12,lane);
  #pragma unroll
  for (int nt=0;nt<4;++nt){
    f32x4 c={0.f,0.f,0.f,0.f};
    c = mm(a0, Bd[l*8+nt*2  ][lane], c);
    c = mm(a1, Bd[l*8+nt*2+1][lane], c);
    stD(dst, nt*16, 0, lane, c, true);
  }
  #pragma unroll
  for (int nt=0;nt<2;++nt){
    f32x4 c={0.f,0.f,0.f,0.f};
    c = mm(av, Bv[l*2+nt][lane], c);
    stD(dst, 64+nt*16, 0, lane, c, true);
  }
  #pragma unroll
  for (int nt=0;nt<2;++nt){
    f32x4 c={0.f,0.f,0.f,0.f};
    c = mm(ae, Be[l*2+nt][lane], c);
    stD(dst, 96+nt*16, 0, lane, c, true);
  }
}

extern "C" __global__ void __launch_bounds__(256,2) mc_main(
    const float* __restrict__ S0p, const float* __restrict__ z,
    const float* __restrict__ dW0, const float* __restrict__ db0,
    const float* __restrict__ dhW, const float* __restrict__ dhb,
    const float* __restrict__ dWo, const float* __restrict__ dbo,
    const float* __restrict__ vW0, const float* __restrict__ vb0,
    const float* __restrict__ vhW, const float* __restrict__ vhb,
    const float* __restrict__ vWo, const float* __restrict__ vbo,
    const float* __restrict__ eW0, const float* __restrict__ eb0,
    const float* __restrict__ ehW, const float* __restrict__ ehb,
    const float* __restrict__ eWo, const float* __restrict__ ebo,
    float* __restrict__ out, float* __restrict__ ws)
{
  __shared__ unsigned short tiles[4][2][2048];   // 32 KB: per-wave ping/pong 16x128 bf16
  __shared__ short8 BdA[24][64];                 // 24 KB
  __shared__ short8 BvA[6][64];                  // 6 KB
  __shared__ short8 BeA[6][64];                  // 6 KB
  __shared__ unsigned short eW0b[2400];          // 4.7 KB (bf16 period rows, 4 mats)
  __shared__ float zper[NSAMP*30];               // 3.75 KB
  __shared__ float dW0s[128], db0s[64], vW0s[64], vb0s[32];
  __shared__ float eW0ts[20], eb0s[20], dWoL[64], eWoL[32];
  __shared__ float SbW[32];

  const int tid  = threadIdx.x;
  const int lane = tid & 63;
  const int wid  = __builtin_amdgcn_readfirstlane(tid >> 6);  // 0..3
  const int blk  = blockIdx.x;
  const int s    = lane >> 3;     // sample 0..7 within wave
  const int c8   = lane & 7;

  unsigned short* T0 = &tiles[wid][0][0];
  unsigned short* T1 = &tiles[wid][1][0];

  for (int q=tid; q<4*2*2048; q+=256) ((unsigned short*)tiles)[q] = 0;

  const float S0v = S0p[0];
  float S = S0v, runmax = S0v, cvE = 0.f;
  float aE[NMAT][4];
  #pragma unroll
  for (int m2=0;m2<NMAT;++m2){ aE[m2][0]=0.f; aE[m2][1]=0.f; aE[m2][2]=0.f; aE[m2][3]=0.f; }
  float G_[4] = {0.f,0.f,0.f,0.f};
  f32x4 rr[6];
  #pragma unroll
  for (int q=0;q<6;++q){ rr[q][0]=0.f; rr[q][1]=0.f; rr[q][2]=0.f; rr[q][3]=0.f; }

  #pragma unroll 1
  for (int p=0;p<NMAT;++p){
    __syncthreads();   // all waves done with previous period's shared data
    // ---- per-period staging ----
    for (int q=tid; q<NSAMP*30; q+=256){ int r2=q/30, c2=q%30; zper[q] = z[(size_t)(blk*NSAMP+r2)*NSTEPS + p*30 + c2]; }
    for (int q=tid; q<2400; q+=256){ int mat=q/600, k=q%600; eW0b[q] = f2bf(eW0[mat*2440 + p*600 + 20 + k]); }
    if (tid < 128){ int rw=tid>>6, j=tid&63; dW0s[tid] = (j<50)? dW0[p*100+rw*50+j] : 0.f; }
    else if (tid < 192){ int j=tid-128; db0s[j] = (j<50)? db0[p*50+j] : ((j==50)? 1.f : 0.f); }
    else { int idx=tid-192, rw=idx>>5, j=idx&31; vW0s[idx] = (j<30)? vW0[p*60+rw*30+j] : 0.f; }
    if (tid < 32)       vb0s[tid] = (tid<30)? vb0[p*30+tid] : ((tid==30)? 1.f : 0.f);
    else if (tid < 52){ int j=tid-32; eW0ts[j]=eW0[p*2440+j]; eb0s[j]=eb0[p*20+j]; }
    else if (tid < 116){ int j=tid-52; dWoL[j] = (j<50)? dWo[p*50+j] : 0.f; }
    else if (tid < 148){ int j=tid-116; eWoL[j] = (j<20)? eWo[p*20+j] : 0.f; }
    // weight fragments (shared, 36 total)
    {
      const float* dhWp = dhW + p*7500; const float* dhbp = dhb + p*150;
      const float* vhWp = vhW + p*2700; const float* vhbp = vhb + p*90;
      const float* ehWp = ehW + p*1200; const float* ehbp = ehb + p*60;
      for (int fid = wid; fid < 36; fid += 4){
        if (fid < 24){
          int l = fid>>3, nt = (fid>>1)&3, kt = fid&1;
          BdA[fid][lane] = mkBd(dhWp + l*2500, dhbp + l*50, nt*16, kt, lane);
        } else if (fid < 30){
          int q = fid-24, l = q>>1, nt = q&1;
          BvA[q][lane] = mkBq(vhWp + l*900, vhbp + l*30, 30, nt*16, lane);
        } else {
          int q = fid-30, l = q>>1, nt = q&1;
          BeA[q][lane] = mkBq(ehWp + l*400, ehbp + l*20, 20, nt*16, lane);
        }
      }
    }
    __syncthreads();

    const float dboS = dbo[p], eboS = ebo[p];

    #pragma unroll 1
    for (int ii=1; ii<=PER; ++ii){
      const float t0  = tgridf(p*PER + ii - 1);
      const float t1  = tgridf(p*PER + ii);
      const float h   = t1 - t0;
      const float sqh = sqrtf(h);

      // ---- phase A: all three H0 -> T0 (wave-private, no barrier) ----
      {
        short8 hv;
        #pragma unroll
        for (int k=0;k<8;++k){
          int j = c8*8 + k;
          float u = fmaxf(fmaf(t0, dW0s[j], fmaf(S, dW0s[64+j], db0s[j])), 0.f);
          hv[k] = (short)f2bf(u);
        }
        *(short8*)((char*)T0 + swaddr(s, c8, 0)) = hv;
        short4v vv;
        #pragma unroll
        for (int k=0;k<4;++k){
          int j = c8*4 + k;
          float u = fmaxf(fmaf(t0, vW0s[j], fmaf(S, vW0s[32+j], vb0s[j])), 0.f);
          vv[k] = (short)f2bf(u);
        }
        *(short4v*)((char*)T0 + swaddr(s, 8+(c8>>1), (c8&1)*8)) = vv;
        short4v ev = {0,0,0,0};
        if (c8 < 5){
          const int o = (ii-1)*20 + c8*4;
          #pragma unroll
          for (int k=0;k<4;++k){
            float w0 = bf2f(eW0b[      o+k]);
            float w1 = bf2f(eW0b[ 600+ o+k]);
            float w2 = bf2f(eW0b[1200+ o+k]);
            float w3 = bf2f(eW0b[1800+ o+k]);
            aE[0][k] = fmaf(S, w0, aE[0][k]);
            aE[1][k] = fmaf(S, w1, aE[1][k]);
            aE[2][k] = fmaf(S, w2, aE[2][k]);
            aE[3][k] = fmaf(S, w3, aE[3][k]);
            float a = (p==0)?aE[0][k]:(p==1)?aE[1][k]:(p==2)?aE[2][k]:aE[3][k];
            int j = c8*4 + k;
            float e0 = fmaxf(t0*eW0ts[j] + a + eb0s[j], 0.f);
            ev[k] = (short)f2bf(e0);
          }
        } else if (c8 == 5){
          ev[0] = (short)0x3F80;   // e 1-propagator at col 20
        }
        *(short4v*)((char*)T0 + swaddr(s, 12+(c8>>1), (c8&1)*8)) = ev;
      }
      // ---- 3 layers, wave-private ping/pong ----
      layer_all(T0, T1, BdA, BvA, BeA, 0, lane);
      layer_all(T1, T0, BdA, BvA, BeA, 1, lane);
      layer_all(T0, T1, BdA, BvA, BeA, 2, lane);
      // ---- heads + scalars + G ----
      {
        float yp = 0.f;
        {
          short8 hv = *(const short8*)((const char*)T1 + swaddr(s, c8, 0));
          #pragma unroll
          for (int k=0;k<8;++k) yp = fmaf(bf2f((unsigned short)hv[k]), dWoL[c8*8+k], yp);
        }
        float yep = 0.f;
        {
          short4v hv = *(const short4v*)((const char*)T1 + swaddr(s, 12+(c8>>1), (c8&1)*8));
          #pragma unroll
          for (int k=0;k<4;++k) yep = fmaf(bf2f((unsigned short)hv[k]), eWoL[c8*4+k], yep);
        }
        #pragma unroll
        for (int mk=1; mk<8; mk<<=1){ yp += __shfl_xor(yp, mk); yep += __shfl_xor(yep, mk); }
        const float y    = yp + dboS;
        const float diff = softplusf(y);
        const float zv   = zper[(wid*8+s)*30 + (ii-1)];
        const float dWn  = sqh * zv;
        const float d1 = 1.f + RRATE*S*sqh;
        const float d2 = 1.f + S*diff*sqh;
        const float Snew = S + RRATE*S*h/d1 + S*diff*dWn/d2;
        const float disc = expf(-RRATE*t0);
        const float coef = disc * S * diff * dWn;
        cvE = fmaf(coef, yep + eboS, cvE);
        runmax = fmaxf(runmax, Snew);
        {
          short4v hv = *(const short4v*)((const char*)T1 + swaddr(s, 8+(c8>>1), (c8&1)*8));
          #pragma unroll
          for (int k=0;k<4;++k) G_[k] = fmaf(coef, bf2f((unsigned short)hv[k]), G_[k]);
        }
        S = Snew;

        if (ii==PER){
          short4v gv;
          #pragma unroll
          for (int k=0;k<4;++k){ gv[k] = (short)f2bf(G_[k]); G_[k] = 0.f; }
          *(short4v*)((char*)T0 + swaddr(s, c8>>1, (c8&1)*8)) = gv;
          if (c8==0) SbW[wid*8+s] = S;
        }
      }

      if (ii==PER){
        // ---- M2 within wave: RR += [G|C]@[vWo;vbo]; pr stats for own 8 samples ----
        short8 a = rdA(T0, 0, 0, lane);
        const float disc_i = expf(-RRATE*t1);
        const float* vWop = vWo + p*2520;
        const float* vbop = vbo + p*84;
        float* pw = (float*)T1;     // per-wave partial scratch (tile free now)
        #pragma unroll
        for (int nt=0;nt<6;++nt){
          const int col = nt*16 + (lane&15);
          short8 bw;
          #pragma unroll
          for (int i2=0;i2<8;++i2){
            int k = ((lane>>4)<<3)+i2;
            float w = 0.f;
            if (col < 84){
              if (k < 30)       w = vWop[k*84+col];
              else if (k == 30) w = vbop[col];
            }
            bw[i2] = (short)f2bf(w);
          }
          f32x4 d4 = {0.f,0.f,0.f,0.f};
          d4 = mm(a,bw,d4);
          const int st = col - p*NSTR;
          const bool inr = (st>=0) && (st<NSTR) && (col<84);
          const float K = strikef(st);
          float ssum=0.f, ssq=0.f;
          #pragma unroll
          for (int i2=0;i2<4;++i2){
            int row = ((lane>>4)<<2) + i2;
            rr[nt][i2] += d4[i2];
            if (row < 8 && inr){
              float pr = disc_i*fmaxf(SbW[wid*8+row]-K,0.f) - rr[nt][i2];
              ssum += pr; ssq = fmaf(pr,pr,ssq);
            }
          }
          ssum += __shfl_down(ssum,16);
          ssq  += __shfl_down(ssq ,16);
          if (inr && lane<16){ pw[st*2] = ssum; pw[st*2+1] = ssq; }
        }
        __syncthreads();
        if (tid < NSTR){
          float v = 0.f;
          #pragma unroll
          for (int w2=0;w2<4;++w2) v += ((const float*)&tiles[w2][1][0])[tid*2];
          ws[WS_PRPART + ((p*NSTR+tid)*2+0)*NBLK + blk] = v;
        } else if (tid >= 64 && tid < 64+NSTR){
          int j = tid-64; float v = 0.f;
          #pragma unroll
          for (int w2=0;w2<4;++w2) v += ((const float*)&tiles[w2][1][0])[j*2+1];
          ws[WS_PRPART + ((p*NSTR+j)*2+1)*NBLK + blk] = v;
        }
      }
    }
  }

  // ---- epilogue ----
  {
    const float discT = expf(-RRATE);
    const float e = discT * (runmax - S);
    if (c8==0) out[OUT_PEXO + blk*NSAMP + wid*8 + s] = e - cvE;
    float se = (c8==0)? e : 0.f;
    se += __shfl_down(se,32); se += __shfl_down(se,16); se += __shfl_down(se,8);
    if (lane==0) ws[WS_EPART + blk*4 + wid] = se;
  }
}

extern "C" __global__ void fin_pv(const float* __restrict__ ws, float* __restrict__ out){
  const int t = threadIdx.x;
  if (t >= NMAT*NSTR) return;
  float sum=0.0f, ssq=0.0f;
  for (int b=0;b<NBLK;++b){
    sum += ws[WS_PRPART + (t*2+0)*NBLK + b];
    ssq += ws[WS_PRPART + (t*2+1)*NBLK + b];
  }
  out[OUT_PV  + t] = sum * (1.0f/MC);
  out[OUT_PVV + t] = (ssq - sum*sum*(1.0f/MC)) * (1.0f/(MC-1));
}

extern "C" __global__ void fin_pe(float* out, float* ws){
  __shared__ float sA[4], sB[4], sC[4];
  const int t = threadIdx.x;
  float sum=0.0f, ssq=0.0f;
  for (int idx=t; idx<MC; idx+=256){
    const float v = out[OUT_PEXO+idx];
    sum += v; ssq = fmaf(v,v,ssq);
  }
  float es = 0.0f;
  for (int idx=t; idx<2048; idx+=256) es += ws[WS_EPART + idx];
  for (int o=32;o>0;o>>=1){
    sum += __shfl_down(sum,o);
    ssq += __shfl_down(ssq,o);
    es  += __shfl_down(es,o);
  }
  const int w=t>>6, lane=t&63;
  if (lane==0){ sA[w]=sum; sB[w]=ssq; sC[w]=es; }
  __syncthreads();
  if (t==0){
    const float s=sA[0]+sA[1]+sA[2]+sA[3];
    const float q=sB[0]+sB[1]+sB[2]+sB[3];
    const float e=sC[0]+sC[1]+sC[2]+sC[3];
    out[OUT_MEAN]=s*(1.0f/MC);
    out[OUT_VAR]=(q - s*s*(1.0f/MC))*(1.0f/(MC-1));
    ws[WS_MEANE]=e*(1.0f/MC);
  }
}

extern "C" __global__ void fin_err(float* out, const float* __restrict__ ws){
  const int m = blockIdx.x*blockDim.x + threadIdx.x;
  if (m < MC) out[OUT_ERR+m] = out[OUT_PEXO+m] - ws[WS_MEANE];
}

extern "C" void kernel_launch(void* const* d_in, const int* in_sizes, int n_in,
                              void* d_out, int out_size, void* d_ws, size_t ws_size,
                              hipStream_t stream){
  (void)in_sizes; (void)n_in; (void)out_size; (void)ws_size;
  const float* S0 =(const float*)d_in[0];
  const float* z  =(const float*)d_in[1];
  const float* dW0=(const float*)d_in[2];
  const float* db0=(const float*)d_in[3];
  const float* dhW=(const float*)d_in[4];
  const float* dhb=(const float*)d_in[5];
  const float* dWo=(const float*)d_in[6];
  const float* dbo=(const float*)d_in[7];
  const float* vW0=(const float*)d_in[8];
  const float* vb0=(const float*)d_in[9];
  const float* vhW=(const float*)d_in[10];
  const float* vhb=(const float*)d_in[11];
  const float* vWo=(const float*)d_in[12];
  const float* vbo=(const float*)d_in[13];
  const float* eW0=(const float*)d_in[14];
  const float* eb0=(const float*)d_in[15];
  const float* ehW=(const float*)d_in[16];
  const float* ehb=(const float*)d_in[17];
  const float* eWo=(const float*)d_in[18];
  const float* ebo=(const float*)d_in[19];
  float* out=(float*)d_out;
  float* ws =(float*)d_ws;

  mc_main<<<dim3(NBLK),dim3(256),0,stream>>>(S0,z,dW0,db0,dhW,dhb,dWo,dbo,
                                             vW0,vb0,vhW,vhb,vWo,vbo,
                                             eW0,eb0,ehW,ehb,eWo,ebo,out,ws);
  fin_pv <<<dim3(1), dim3(128),0,stream>>>(ws,out);
  fin_pe <<<dim3(1), dim3(256),0,stream>>>(out,ws);
  fin_err<<<dim3(64),dim3(256),0,stream>>>(out,ws);
}

// Round 11
// 445.290 us; speedup vs baseline: 1.3190x; 1.3190x over previous
//
#include <hip/hip_runtime.h>
#include <hip/hip_bf16.h>
#include <math.h>

#define MC      16384
#define NSTEPS  120
#define PER     30
#define NMAT    4
#define NSTR    21
#define RRATE   0.05f
#define NBLK    512
#define NSAMP   32
#define HSTEP   (1.0f/120.0f)
#define SQH     0.09128709291752769f   // sqrt(1/120)

typedef short short8  __attribute__((ext_vector_type(8)));
typedef short short4v __attribute__((ext_vector_type(4)));
typedef float f32x4   __attribute__((ext_vector_type(4)));

// ws layout (floats)
#define WS_PRPART 0                         // [84][2][512]
#define WS_EPART  (NMAT*NSTR*2*NBLK)        // [512]
#define WS_MEANE  (WS_EPART + NBLK)         // [1]

// out layout (floats)
#define OUT_PV    0
#define OUT_PVV   84
#define OUT_PEXO  168
#define OUT_MEAN  16552
#define OUT_VAR   16553
#define OUT_ERR   16554

__device__ __forceinline__ float tgridf(int i)  { return (float)i * HSTEP; }
__device__ __forceinline__ float strikef(int s) { return (float)(0.8 + (double)s * 0.02); }
__device__ __forceinline__ float softplusf(float x){
  return fmaxf(x, 0.0f) + __logf(1.0f + __expf(-fabsf(x)));
}
__device__ __forceinline__ unsigned short f2bf(float f){
  __hip_bfloat16 b = __float2bfloat16(f);           // compiler emits v_cvt_pk_bf16_f32, pairs casts
  return __builtin_bit_cast(unsigned short, b);
}
__device__ __forceinline__ float bf2f(unsigned short u){
  return __builtin_bit_cast(float, ((unsigned)u)<<16);
}
// swizzled byte addr in [32 rows x 128 cols] bf16 tile (256 B/row, 16 slots of 16B)
__device__ __forceinline__ int swaddr(int row, int slot, int inner){
  return row*256 + (((slot + row) & 15) << 4) + inner;
}
__device__ __forceinline__ short8 rdA(const unsigned short* H, int mt, int base, int lane){
  int addr = swaddr(mt*16 + (lane&15), base + (lane>>4), 0);
  return *(const short8*)((const char*)H + addr);
}
__device__ __forceinline__ f32x4 mm(short8 a, short8 b, f32x4 c){
  return __builtin_amdgcn_mfma_f32_16x16x32_bf16(a, b, c, 0, 0, 0);
}
// D-store (relu); bias folded into MFMA via constant-1 K-row
__device__ __forceinline__ void stD(unsigned short* H, int colbase, int mt, int lane,
                                    f32x4 acc, bool relu){
  int col  = colbase + (lane & 15);
  int slot = col >> 3, inner = (col & 7)*2;
  #pragma unroll
  for (int i2=0;i2<4;++i2){
    int rw = mt*16 + ((lane>>4)<<2) + i2;
    float v = acc[i2];
    if (relu) v = fmaxf(v, 0.0f);
    *(unsigned short*)((char*)H + swaddr(rw, slot, inner)) = f2bf(v);
  }
}
// d-net B frag with bias row at k==50 and 1-propagator at (50,50)
__device__ __forceinline__ short8 mkBd(const float* __restrict__ W, const float* __restrict__ bias,
                                       int n0, int kt, int lane){
  short8 r;
  int n = n0 + (lane&15);
  #pragma unroll
  for (int i2=0;i2<8;++i2){
    int k = kt*32 + ((lane>>4)<<3) + i2;
    float w;
    if (k<50)       w = (n<50)? W[k*50+n] : 0.f;
    else if (k==50) w = (n<50)? bias[n] : ((n==50)? 1.f : 0.f);
    else            w = 0.f;
    r[i2] = (short)f2bf(w);
  }
  return r;
}
// v/e-net B frag (K tile 0..31) with bias row at k==KV, 1-propagator at (KV,KV)
__device__ __forceinline__ short8 mkBq(const float* __restrict__ W, const float* __restrict__ bias,
                                       int KV, int n0, int lane){
  short8 r;
  int n = n0 + (lane&15);
  #pragma unroll
  for (int i2=0;i2<8;++i2){
    int k = ((lane>>4)<<3) + i2;
    float w;
    if (k<KV)       w = (n<KV)? W[k*KV+n] : 0.f;
    else if (k==KV) w = (n<KV)? bias[n] : ((n==KV)? 1.f : 0.f);
    else            w = 0.f;
    r[i2] = (short)f2bf(w);
  }
  return r;
}

extern "C" __global__ void __launch_bounds__(256,2) mc_main(
    const float* __restrict__ S0p, const float* __restrict__ z,
    const float* __restrict__ dW0, const float* __restrict__ db0,
    const float* __restrict__ dhW, const float* __restrict__ dhb,
    const float* __restrict__ dWo, const float* __restrict__ dbo,
    const float* __restrict__ vW0, const float* __restrict__ vb0,
    const float* __restrict__ vhW, const float* __restrict__ vhb,
    const float* __restrict__ vWo, const float* __restrict__ vbo,
    const float* __restrict__ eW0, const float* __restrict__ eb0,
    const float* __restrict__ ehW, const float* __restrict__ ehb,
    const float* __restrict__ eWo, const float* __restrict__ ebo,
    float* __restrict__ out, float* __restrict__ ws)
{
  __shared__ unsigned short Hb0[NSAMP*128];   // 8 KB
  __shared__ unsigned short Hb1[NSAMP*128];   // 8 KB
  __shared__ short8 BqL[4][3][64];            // 12 KB
  __shared__ short8 BdL[4][6][64];            // 24 KB
  __shared__ float vh3f[NSAMP*40];            // 5 KB
  __shared__ float zper[NSAMP*30];            // 3.75 KB
  __shared__ float eW0per[NMAT*600];          // 9.375 KB
  __shared__ float dW0s[128];
  __shared__ float db0s[64];
  __shared__ float vW0s[64];
  __shared__ float vb0s[32];
  __shared__ float eW0ts[20];
  __shared__ float eb0s[20];
  __shared__ float dWoL[64];
  __shared__ float eWoL[32];
  __shared__ float dtab[PER];
  __shared__ float Sb[NSAMP], ebuf[NSAMP];
  __shared__ float part[2*84*2];

  const int tid  = threadIdx.x;
  const int lane = tid & 63;
  const int wid  = __builtin_amdgcn_readfirstlane(tid >> 6);  // 0..3
  const int blk  = blockIdx.x;
  const int r    = tid >> 3;          // sample row 0..31
  const int cc   = tid & 7;

  // wave roles
  const int  ntd = wid;
  const bool isv = (wid < 2);
  const int  ntq = wid & 1;

  const float S0v = S0p[0];
  float S = S0v, runmax = S0v, cvE = 0.f;
  f32x4 rr[3];
  #pragma unroll
  for (int q=0;q<3;++q){ rr[q][0]=0.f; rr[q][1]=0.f; rr[q][2]=0.f; rr[q][3]=0.f; }
  float aE[NMAT][4];
  #pragma unroll
  for (int mt2=0;mt2<NMAT;++mt2){ aE[mt2][0]=0.f; aE[mt2][1]=0.f; aE[mt2][2]=0.f; aE[mt2][3]=0.f; }
  float G_[4] = {0.f,0.f,0.f,0.f};

  #pragma unroll 1
  for (int p=0;p<NMAT;++p){
    // ---- per-period staging ----
    for (int q=tid; q<NSAMP*30; q+=256){ int r2=q/30, c2=q%30; zper[q] = z[(size_t)(blk*NSAMP+r2)*NSTEPS + p*30 + c2]; }
    for (int q=tid; q<NMAT*600; q+=256){ int mat=q/600, k=q%600; eW0per[q] = eW0[mat*2440 + p*600 + 20 + k]; }
    if (tid < 128){
      int rw = tid>>6, j = tid&63;
      dW0s[tid] = (j<50)? dW0[p*100 + rw*50 + j] : 0.f;
    } else if (tid < 192){
      int j = tid-128;
      db0s[j] = (j<50)? db0[p*50+j] : ((j==50)? 1.f : 0.f);
    } else {
      int idx = tid-192, rw = idx>>5, j = idx&31;
      vW0s[idx] = (j<30)? vW0[p*60 + rw*30 + j] : 0.f;
    }
    if (tid < 32)       vb0s[tid] = (tid<30)? vb0[p*30+tid] : ((tid==30)? 1.f : 0.f);
    else if (tid < 52){ int j=tid-32; eW0ts[j]=eW0[p*2440+j]; eb0s[j]=eb0[p*20+j]; }
    else if (tid < 116){ int j=tid-52; dWoL[j] = (j<50)? dWo[p*50+j] : 0.f; }
    else if (tid < 148){ int j=tid-116; eWoL[j] = (j<20)? eWo[p*20+j] : 0.f; }
    else if (tid < 148+PER){ int j=tid-148; dtab[j] = __expf(-RRATE * ((float)(p*PER+j) * HSTEP)); }

    const float dboS = dbo[p], eboS = ebo[p];

    // ALL B-fragments LDS-resident (built once per period)
    const float* dhWp = dhW + p*7500;
    const float* dhbp = dhb + p*150;
    BdL[wid][0][lane] = mkBd(dhWp,      dhbp,     ntd*16, 0, lane);
    BdL[wid][1][lane] = mkBd(dhWp,      dhbp,     ntd*16, 1, lane);
    BdL[wid][2][lane] = mkBd(dhWp+2500, dhbp+50,  ntd*16, 0, lane);
    BdL[wid][3][lane] = mkBd(dhWp+2500, dhbp+50,  ntd*16, 1, lane);
    BdL[wid][4][lane] = mkBd(dhWp+5000, dhbp+100, ntd*16, 0, lane);
    BdL[wid][5][lane] = mkBd(dhWp+5000, dhbp+100, ntd*16, 1, lane);
    {
      const float* qW    = isv ? (vhW + p*2700) : (ehW + p*1200);
      const float* qb    = isv ? (vhb + p*90)   : (ehb + p*60);
      const int    qstep = isv ? 900 : 400;
      const int    qN    = isv ? 30  : 20;
      BqL[wid][0][lane] = mkBq(qW,         qb,        qN, ntq*16, lane);
      BqL[wid][1][lane] = mkBq(qW+qstep,   qb+qN,     qN, ntq*16, lane);
      BqL[wid][2][lane] = mkBq(qW+2*qstep, qb+2*qN,   qN, ntq*16, lane);
    }
    const int qbase = isv ? 8 : 12;
    const int qcolb = (isv?64:96) + ntq*16;

    __syncthreads();

    #pragma unroll 1
    for (int ii=1; ii<=PER; ++ii){
      const float t0  = tgridf(p*PER + ii - 1);

      // ======== phase A: all three H0 -> Hb0 ========
      {
        short8 hv;
        #pragma unroll
        for (int k=0;k<8;++k){
          int j = cc*8 + k;
          float u = fmaxf(fmaf(t0, dW0s[j], fmaf(S, dW0s[64+j], db0s[j])), 0.f);
          hv[k] = (short)f2bf(u);
        }
        *(short8*)((char*)Hb0 + swaddr(r, cc, 0)) = hv;
        short4v vv;
        #pragma unroll
        for (int k=0;k<4;++k){
          int j = cc*4 + k;
          float u = fmaxf(fmaf(t0, vW0s[j], fmaf(S, vW0s[32+j], vb0s[j])), 0.f);
          vv[k] = (short)f2bf(u);
        }
        *(short4v*)((char*)Hb0 + swaddr(r, 8+(cc>>1), (cc&1)*8)) = vv;
        short4v ev = {0,0,0,0};
        if (cc < 5){
          const int o = (ii-1)*20 + cc*4;
          f32x4 w0 = *(const f32x4*)&eW0per[        o];
          f32x4 w1 = *(const f32x4*)&eW0per[ 600 +  o];
          f32x4 w2 = *(const f32x4*)&eW0per[1200 +  o];
          f32x4 w3 = *(const f32x4*)&eW0per[1800 +  o];
          #pragma unroll
          for (int k=0;k<4;++k){
            aE[0][k] = fmaf(S, w0[k], aE[0][k]);
            aE[1][k] = fmaf(S, w1[k], aE[1][k]);
            aE[2][k] = fmaf(S, w2[k], aE[2][k]);
            aE[3][k] = fmaf(S, w3[k], aE[3][k]);
            float a = (p==0)?aE[0][k]:(p==1)?aE[1][k]:(p==2)?aE[2][k]:aE[3][k];
            int j = cc*4 + k;
            float e0 = fmaxf(t0*eW0ts[j] + a + eb0s[j], 0.f);
            ev[k] = (short)f2bf(e0);
          }
        } else if (cc == 5){
          ev[0] = (short)0x3F80;   // bf16 1.0 at e-col 20 (bias propagator)
        }
        *(short4v*)((char*)Hb0 + swaddr(r, 12+(cc>>1), (cc&1)*8)) = ev;
      }
      __syncthreads();
      // ======== phase B: L1  Hb0 -> Hb1 ========
      {
        short8 b0 = BdL[wid][0][lane], b1 = BdL[wid][1][lane];
        short8 a00=rdA(Hb0,0,0,lane), a01=rdA(Hb0,0,4,lane);
        short8 a10=rdA(Hb0,1,0,lane), a11=rdA(Hb0,1,4,lane);
        f32x4 c0={0.f,0.f,0.f,0.f}, c1={0.f,0.f,0.f,0.f};
        c0=mm(a00,b0,c0); c0=mm(a01,b1,c0);
        c1=mm(a10,b0,c1); c1=mm(a11,b1,c1);
        stD(Hb1, ntd*16, 0, lane, c0, true);
        stD(Hb1, ntd*16, 1, lane, c1, true);
        short8 Bq = BqL[wid][0][lane];
        short8 q0=rdA(Hb0,0,qbase,lane), q1=rdA(Hb0,1,qbase,lane);
        f32x4 cq0={0.f,0.f,0.f,0.f}, cq1={0.f,0.f,0.f,0.f};
        cq0=mm(q0,Bq,cq0); cq1=mm(q1,Bq,cq1);
        stD(Hb1, qcolb, 0, lane, cq0, true);
        stD(Hb1, qcolb, 1, lane, cq1, true);
      }
      __syncthreads();
      // ======== phase C: L2  Hb1 -> Hb0 ========
      {
        short8 b0 = BdL[wid][2][lane], b1 = BdL[wid][3][lane];
        short8 a00=rdA(Hb1,0,0,lane), a01=rdA(Hb1,0,4,lane);
        short8 a10=rdA(Hb1,1,0,lane), a11=rdA(Hb1,1,4,lane);
        f32x4 c0={0.f,0.f,0.f,0.f}, c1={0.f,0.f,0.f,0.f};
        c0=mm(a00,b0,c0); c0=mm(a01,b1,c0);
        c1=mm(a10,b0,c1); c1=mm(a11,b1,c1);
        stD(Hb0, ntd*16, 0, lane, c0, true);
        stD(Hb0, ntd*16, 1, lane, c1, true);
        short8 Bq = BqL[wid][1][lane];
        short8 q0=rdA(Hb1,0,qbase,lane), q1=rdA(Hb1,1,qbase,lane);
        f32x4 cq0={0.f,0.f,0.f,0.f}, cq1={0.f,0.f,0.f,0.f};
        cq0=mm(q0,Bq,cq0); cq1=mm(q1,Bq,cq1);
        stD(Hb0, qcolb, 0, lane, cq0, true);
        stD(Hb0, qcolb, 1, lane, cq1, true);
      }
      __syncthreads();
      // ======== phase D: L3  Hb0 -> Hb1 (v-net -> vh3f f32) ========
      {
        short8 b0 = BdL[wid][4][lane], b1 = BdL[wid][5][lane];
        short8 a00=rdA(Hb0,0,0,lane), a01=rdA(Hb0,0,4,lane);
        short8 a10=rdA(Hb0,1,0,lane), a11=rdA(Hb0,1,4,lane);
        f32x4 c0={0.f,0.f,0.f,0.f}, c1={0.f,0.f,0.f,0.f};
        c0=mm(a00,b0,c0); c0=mm(a01,b1,c0);
        c1=mm(a10,b0,c1); c1=mm(a11,b1,c1);
        stD(Hb1, ntd*16, 0, lane, c0, true);
        stD(Hb1, ntd*16, 1, lane, c1, true);
        short8 Bq = BqL[wid][2][lane];
        short8 q0=rdA(Hb0,0,qbase,lane), q1=rdA(Hb0,1,qbase,lane);
        f32x4 cq0={0.f,0.f,0.f,0.f}, cq1={0.f,0.f,0.f,0.f};
        cq0=mm(q0,Bq,cq0); cq1=mm(q1,Bq,cq1);
        if (isv){
          #pragma unroll
          for (int i2=0;i2<4;++i2){
            int r0 = ((lane>>4)<<2) + i2;
            vh3f[ r0     *40 + ntq*16 + (lane&15)] = fmaxf(cq0[i2], 0.f);
            vh3f[(16+r0) *40 + ntq*16 + (lane&15)] = fmaxf(cq1[i2], 0.f);
          }
        } else {
          stD(Hb1, qcolb, 0, lane, cq0, true);
          stD(Hb1, qcolb, 1, lane, cq1, true);
        }
      }
      __syncthreads();
      // ======== phase F: heads + scalars + G-accum (+ M1 at period end) ========
      {
        float yp = 0.f;
        {
          short8 hv = *(const short8*)((const char*)Hb1 + swaddr(r, cc, 0));
          #pragma unroll
          for (int k=0;k<8;++k) yp = fmaf(bf2f((unsigned short)hv[k]), dWoL[cc*8+k], yp);
        }
        float yep = 0.f;
        if (cc < 5){
          short4v hv = *(const short4v*)((const char*)Hb1 + swaddr(r, 12+(cc>>1), (cc&1)*8));
          #pragma unroll
          for (int k=0;k<4;++k) yep = fmaf(bf2f((unsigned short)hv[k]), eWoL[cc*4+k], yep);
        }
        #pragma unroll
        for (int mk=1; mk<8; mk<<=1){ yp += __shfl_xor(yp, mk); yep += __shfl_xor(yep, mk); }
        const float y    = yp + dboS;
        const float diff = softplusf(y);
        const float zv   = zper[r*30 + (ii-1)];
        const float dWn  = SQH * zv;
        const float d1 = 1.f + (RRATE*SQH)*S;
        const float d2 = 1.f + S*diff*SQH;
        const float Snew = S + (RRATE*HSTEP)*S*__builtin_amdgcn_rcpf(d1)
                             + S*diff*dWn*__builtin_amdgcn_rcpf(d2);
        const float disc = dtab[ii-1];
        const float coef = disc * S * diff * dWn;
        cvE = fmaf(coef, yep + eboS, cvE);
        runmax = fmaxf(runmax, Snew);
        {
          f32x4 vv = *(const f32x4*)&vh3f[r*40 + cc*4];  // col 30 == 1.0 -> G[30] = C
          #pragma unroll
          for (int k=0;k<4;++k) G_[k] = fmaf(coef, vv[k], G_[k]);
        }
        S = Snew;

        if (ii==PER){
          short4v gv;
          #pragma unroll
          for (int k=0;k<4;++k){ gv[k] = (short)f2bf(G_[k]); G_[k] = 0.f; }
          *(short4v*)((char*)Hb0 + swaddr(r, cc>>1, (cc&1)*8)) = gv;
          if (cc==0) Sb[r] = S;
        }
      }

      if (ii==PER){
        __syncthreads();
        // ======== M2: RR += [G|C] @ [vWo;vbo] ; pr stats (12 tiles / 4 waves) ========
        const float disc_i = __expf(-RRATE * ((float)(p+1) * 0.25f));
        const float* vWop = vWo + p*2520;
        const float* vbop = vbo + p*84;
        #pragma unroll
        for (int q3=0;q3<3;++q3){
          const int T = wid*3 + q3;           // 0..11
          const int mtr = T/6, ntr = T%6;
          short8 a = rdA(Hb0, mtr, 0, lane);
          const int col = ntr*16 + (lane&15);
          short8 bw;
          #pragma unroll
          for (int i2=0;i2<8;++i2){
            int k = ((lane>>4)<<3)+i2;
            float w = 0.f;
            if (col < 84){
              if (k < 30)       w = vWop[k*84+col];
              else if (k == 30) w = vbop[col];
            }
            bw[i2] = (short)f2bf(w);
          }
          f32x4 d4 = {0.f,0.f,0.f,0.f};
          d4 = mm(a,bw,d4);
          const int s = col - p*NSTR;
          const bool inr = (s>=0) && (s<NSTR) && (col<84);
          const float K = strikef(s);
          float ssum=0.f, ssq=0.f;
          #pragma unroll
          for (int i2=0;i2<4;++i2){
            int row = mtr*16 + ((lane>>4)<<2) + i2;
            rr[q3][i2] += d4[i2];
            if (inr){
              float pr = disc_i*fmaxf(Sb[row]-K,0.f) - rr[q3][i2];
              ssum += pr; ssq = fmaf(pr,pr,ssq);
            }
          }
          ssum += __shfl_down(ssum,16); ssum += __shfl_down(ssum,32);
          ssq  += __shfl_down(ssq ,16); ssq  += __shfl_down(ssq ,32);
          if (inr && lane<16){
            part[(mtr*84+col)*2+0] = ssum;
            part[(mtr*84+col)*2+1] = ssq;
          }
        }
        __syncthreads();
        // ======== M3: write per-block partials ========
        if (tid < NSTR){
          int cidx = p*NSTR + tid;
          ws[WS_PRPART + (cidx*2+0)*NBLK + blk] = part[cidx*2] + part[(84+cidx)*2];
        } else if (tid >= 64 && tid < 64+NSTR){
          int cidx = p*NSTR + (tid-64);
          ws[WS_PRPART + (cidx*2+1)*NBLK + blk] = part[cidx*2+1] + part[(84+cidx)*2+1];
        }
        __syncthreads();   // protect LDS (dWoL etc.) from next period's staging writes
      }
    }
  }

  // ---- epilogue ----
  if (cc==0){
    const float discT = __expf(-RRATE);
    const float e = discT * (runmax - S);
    out[OUT_PEXO + blk*NSAMP + r] = e - cvE;
    ebuf[r] = e;
  }
  __syncthreads();
  if (tid < 32){
    float se = ebuf[tid];
    se += __shfl_down(se,16); se += __shfl_down(se,8);
    se += __shfl_down(se,4);  se += __shfl_down(se,2); se += __shfl_down(se,1);
    if (tid==0) ws[WS_EPART + blk] = se;
  }
}

extern "C" __global__ void fin_pv(const float* __restrict__ ws, float* __restrict__ out){
  const int t = threadIdx.x;
  if (t >= NMAT*NSTR) return;
  float sum=0.0f, ssq=0.0f;
  for (int b=0;b<NBLK;++b){
    sum += ws[WS_PRPART + (t*2+0)*NBLK + b];
    ssq += ws[WS_PRPART + (t*2+1)*NBLK + b];
  }
  out[OUT_PV  + t] = sum * (1.0f/MC);
  out[OUT_PVV + t] = (ssq - sum*sum*(1.0f/MC)) * (1.0f/(MC-1));
}

extern "C" __global__ void fin_pe(float* out, float* ws){
  __shared__ float sA[4], sB[4], sC[4];
  const int t = threadIdx.x;
  float sum=0.0f, ssq=0.0f;
  for (int idx=t; idx<MC; idx+=256){
    const float v = out[OUT_PEXO+idx];
    sum += v; ssq = fmaf(v,v,ssq);
  }
  float es = ws[WS_EPART + t] + ws[WS_EPART + 256 + t];
  for (int o=32;o>0;o>>=1){
    sum += __shfl_down(sum,o);
    ssq += __shfl_down(ssq,o);
    es  += __shfl_down(es,o);
  }
  const int w=t>>6, lane=t&63;
  if (lane==0){ sA[w]=sum; sB[w]=ssq; sC[w]=es; }
  __syncthreads();
  if (t==0){
    const float s=sA[0]+sA[1]+sA[2]+sA[3];
    const float q=sB[0]+sB[1]+sB[2]+sB[3];
    const float e=sC[0]+sC[1]+sC[2]+sC[3];
    out[OUT_MEAN]=s*(1.0f/MC);
    out[OUT_VAR]=(q - s*s*(1.0f/MC))*(1.0f/(MC-1));
    ws[WS_MEANE]=e*(1.0f/MC);
  }
}

extern "C" __global__ void fin_err(float* out, const float* __restrict__ ws){
  const int m = blockIdx.x*blockDim.x + threadIdx.x;
  if (m < MC) out[OUT_ERR+m] = out[OUT_PEXO+m] - ws[WS_MEANE];
}

extern "C" void kernel_launch(void* const* d_in, const int* in_sizes, int n_in,
                              void* d_out, int out_size, void* d_ws, size_t ws_size,
                              hipStream_t stream){
  (void)in_sizes; (void)n_in; (void)out_size; (void)ws_size;
  const float* S0 =(const float*)d_in[0];
  const float* z  =(const float*)d_in[1];
  const float* dW0=(const float*)d_in[2];
  const float* db0=(const float*)d_in[3];
  const float* dhW=(const float*)d_in[4];
  const float* dhb=(const float*)d_in[5];
  const float* dWo=(const float*)d_in[6];
  const float* dbo=(const float*)d_in[7];
  const float* vW0=(const float*)d_in[8];
  const float* vb0=(const float*)d_in[9];
  const float* vhW=(const float*)d_in[10];
  const float* vhb=(const float*)d_in[11];
  const float* vWo=(const float*)d_in[12];
  const float* vbo=(const float*)d_in[13];
  const float* eW0=(const float*)d_in[14];
  const float* eb0=(const float*)d_in[15];
  const float* ehW=(const float*)d_in[16];
  const float* ehb=(const float*)d_in[17];
  const float* eWo=(const float*)d_in[18];
  const float* ebo=(const float*)d_in[19];
  float* out=(float*)d_out;
  float* ws =(float*)d_ws;

  mc_main<<<dim3(NBLK),dim3(256),0,stream>>>(S0,z,dW0,db0,dhW,dhb,dWo,dbo,
                                             vW0,vb0,vhW,vhb,vWo,vbo,
                                             eW0,eb0,ehW,ehb,eWo,ebo,out,ws);
  fin_pv <<<dim3(1), dim3(128),0,stream>>>(ws,out);
  fin_pe <<<dim3(1), dim3(256),0,stream>>>(out,ws);
  fin_err<<<dim3(64),dim3(256),0,stream>>>(out,ws);
}